// Round 1
// baseline (10980.546 us; speedup 1.0000x reference)
//
#include <hip/hip_runtime.h>
#include <hip/hip_bf16.h>

#define NN 20000
#define NE 320000
#define RR 8
#define DD 256
#define LL 6
#define EED 32
#define BB 64
#define KK 32
#define BM 32
#define BK 32

__global__ __launch_bounds__(256) void deg_kernel(const int* __restrict__ dstv,
                                                  float* __restrict__ deg) {
    int e = blockIdx.x * 256 + threadIdx.x;
    if (e < NE) unsafeAtomicAdd(&deg[dstv[e]], 1.0f);
}

__global__ __launch_bounds__(256) void invdeg_kernel(float* __restrict__ deg) {
    int i = blockIdx.x * 256 + threadIdx.x;
    if (i < NN) deg[i] = 1.0f / fmaxf(deg[i], 1.0f);
}

__global__ __launch_bounds__(256) void init_x_kernel(float* __restrict__ x) {
    int i = blockIdx.x * 256 + threadIdx.x;
    ((float4*)x)[i] = make_float4(1.f, 1.f, 1.f, 1.f);
}

// One wave per edge: proj = ee[e] @ We[l] (We in LDS), msg = x[src] + proj,
// atomicAdd into agg[(rel*NN + dst)*DD + d].
__global__ __launch_bounds__(256) void scatter_kernel(
    const int* __restrict__ srcv, const int* __restrict__ dstv,
    const int* __restrict__ typev, const float* __restrict__ ee,
    const float* __restrict__ We_l, const float* __restrict__ x,
    float* __restrict__ agg)
{
    __shared__ float Ws[EED * DD];
    int tid = threadIdx.x;
#pragma unroll
    for (int i = 0; i < 8; ++i)
        *(float4*)&Ws[tid * 4 + i * 1024] = *(const float4*)&We_l[tid * 4 + i * 1024];
    __syncthreads();
    int wave = tid >> 6, lane = tid & 63;
    int e = blockIdx.x * 4 + wave;
    int s = srcv[e], d = dstv[e], r = typev[e];
    float ev = (lane < EED) ? ee[e * EED + lane] : 0.0f;
    float4 xv = *(const float4*)&x[(size_t)s * DD + lane * 4];
    float4 acc = make_float4(0.f, 0.f, 0.f, 0.f);
#pragma unroll
    for (int k = 0; k < EED; ++k) {
        float ek = __shfl(ev, k);
        float4 wv = *(const float4*)&Ws[k * DD + lane * 4];
        acc.x += ek * wv.x; acc.y += ek * wv.y;
        acc.z += ek * wv.z; acc.w += ek * wv.w;
    }
    float* p = &agg[((size_t)r * NN + d) * DD + lane * 4];
    unsafeAtomicAdd(p + 0, xv.x + acc.x);
    unsafeAtomicAdd(p + 1, xv.y + acc.y);
    unsafeAtomicAdd(p + 2, xv.z + acc.z);
    unsafeAtomicAdd(p + 3, xv.w + acc.w);
}

// h[n][f] = invdeg[n] * sum_{r,k} agg[r][n][k] * W[l][r][k][f]
//           + sum_k x[n][k] * Wself[l][k][f]
// Unified K = RR*DD (agg, scaled by invdeg) + DD (x part).
// Then LN + relu + residual, in-place update of x. BM=32 rows per block.
__global__ __launch_bounds__(256) void gemm_ln_kernel(
    const float* __restrict__ agg, const float* __restrict__ Wl,
    const float* __restrict__ Wsl, const float* __restrict__ invdeg,
    const float* __restrict__ gl, const float* __restrict__ bl,
    float* __restrict__ x)
{
    __shared__ float As[BM * BK];
    __shared__ float Bs[BK * DD];   // reused as h tile after K-loop
    int tid = threadIdx.x;
    int row0 = blockIdx.x * BM;
    int tr = tid >> 5, tc = tid & 31;           // 8 x 32 thread grid
    float acc[4][8] = {};
    int ar = tid >> 3, ac = (tid & 7) * 4;      // A-tile loader coords
    float idg = invdeg[row0 + ar];

    for (int kb = 0; kb < RR * DD + DD; kb += BK) {
        // A tile load (32x32)
        {
            int kg = kb + ac;
            float4 av;
            if (kg < RR * DD) {
                av = *(const float4*)&agg[(((size_t)(kg >> 8)) * NN + row0 + ar) * DD + (kg & 255)];
                av.x *= idg; av.y *= idg; av.z *= idg; av.w *= idg;
            } else {
                av = *(const float4*)&x[(size_t)(row0 + ar) * DD + (kg - RR * DD)];
            }
            *(float4*)&As[ar * BK + ac] = av;
        }
        // B tile load (32x256): rows kb..kb+31 of stacked [W[l]; Wself[l]]
#pragma unroll
        for (int i = 0; i < 8; ++i) {
            int f = tid * 4 + i * 1024;
            int br = f >> 8, bc = f & 255;
            int kgb = kb + br;
            const float* Bp = (kgb < RR * DD) ? &Wl[(size_t)kgb * DD + bc]
                                              : &Wsl[(size_t)(kgb - RR * DD) * DD + bc];
            *(float4*)&Bs[br * DD + bc] = *(const float4*)Bp;
        }
        __syncthreads();
#pragma unroll
        for (int k = 0; k < BK; ++k) {
            float4 b0 = *(float4*)&Bs[k * DD + tc * 4];
            float4 b1 = *(float4*)&Bs[k * DD + 128 + tc * 4];
#pragma unroll
            for (int i = 0; i < 4; ++i) {
                float a = As[(tr * 4 + i) * BK + k];
                acc[i][0] += a * b0.x; acc[i][1] += a * b0.y;
                acc[i][2] += a * b0.z; acc[i][3] += a * b0.w;
                acc[i][4] += a * b1.x; acc[i][5] += a * b1.y;
                acc[i][6] += a * b1.z; acc[i][7] += a * b1.w;
            }
        }
        __syncthreads();
    }
    // dump h tile into Bs (32x256)
#pragma unroll
    for (int i = 0; i < 4; ++i) {
        int row = tr * 4 + i;
        *(float4*)&Bs[row * DD + tc * 4]       = make_float4(acc[i][0], acc[i][1], acc[i][2], acc[i][3]);
        *(float4*)&Bs[row * DD + 128 + tc * 4] = make_float4(acc[i][4], acc[i][5], acc[i][6], acc[i][7]);
    }
    __syncthreads();
    // LN + relu + residual; wave handles 8 rows, lane covers 4 cols
    int wave = tid >> 6, lane = tid & 63;
    float4 g  = *(const float4*)&gl[lane * 4];
    float4 bb = *(const float4*)&bl[lane * 4];
#pragma unroll
    for (int rr = 0; rr < 8; ++rr) {
        int row = wave * 8 + rr;
        float4 v = *(float4*)&Bs[row * DD + lane * 4];
        float s = v.x + v.y + v.z + v.w;
        float q = v.x * v.x + v.y * v.y + v.z * v.z + v.w * v.w;
#pragma unroll
        for (int off = 32; off; off >>= 1) {
            s += __shfl_xor(s, off);
            q += __shfl_xor(q, off);
        }
        float mu  = s * (1.0f / DD);
        float var = q * (1.0f / DD) - mu * mu;
        float rs  = rsqrtf(var + 1e-5f);
        size_t xi = (size_t)(row0 + row) * DD + lane * 4;
        float4 xv = *(const float4*)&x[xi];
        float4 o;
        o.x = fmaxf((v.x - mu) * rs * g.x + bb.x, 0.0f) + xv.x;
        o.y = fmaxf((v.y - mu) * rs * g.y + bb.y, 0.0f) + xv.y;
        o.z = fmaxf((v.z - mu) * rs * g.z + bb.z, 0.0f) + xv.z;
        o.w = fmaxf((v.w - mu) * rs * g.w + bb.w, 0.0f) + xv.w;
        *(float4*)&x[xi] = o;
    }
}

__global__ __launch_bounds__(256) void score_kernel(
    const int* __restrict__ batch, const float* __restrict__ x,
    const float* __restrict__ rel_emb, float* __restrict__ out)
{
    int tid = threadIdx.x;
    int wave = tid >> 6, lane = tid & 63;
    int idx = blockIdx.x * 4 + wave;
    int s = batch[idx * 3 + 0], t = batch[idx * 3 + 1], r = batch[idx * 3 + 2];
    float4 sv = *(const float4*)&x[(size_t)s * DD + lane * 4];
    float4 tv = *(const float4*)&x[(size_t)t * DD + lane * 4];
    float4 rv = *(const float4*)&rel_emb[(size_t)r * DD + lane * 4];
    float sum = sv.x * rv.x * tv.x + sv.y * rv.y * tv.y +
                sv.z * rv.z * tv.z + sv.w * rv.w * tv.w;
#pragma unroll
    for (int off = 32; off; off >>= 1) sum += __shfl_xor(sum, off);
    if (lane == 0) out[idx] = sum;
}

extern "C" void kernel_launch(void* const* d_in, const int* in_sizes, int n_in,
                              void* d_out, int out_size, void* d_ws, size_t ws_size,
                              hipStream_t stream)
{
    const int*   edge_index = (const int*)d_in[0];
    const int*   srcv   = edge_index;
    const int*   dstv   = edge_index + NE;
    const int*   typev  = (const int*)d_in[1];
    const float* ee     = (const float*)d_in[2];
    const int*   batch  = (const int*)d_in[3];
    const float* W      = (const float*)d_in[4];
    const float* Wself  = (const float*)d_in[5];
    const float* We     = (const float*)d_in[6];
    const float* gamma  = (const float*)d_in[7];
    const float* beta   = (const float*)d_in[8];
    const float* rel_emb= (const float*)d_in[9];
    float* out = (float*)d_out;

    float* agg = (float*)d_ws;                        // RR*NN*DD floats (163.84 MB)
    float* x   = agg + (size_t)RR * NN * DD;          // NN*DD floats (20.48 MB)
    float* deg = x + (size_t)NN * DD;                 // NN floats

    hipMemsetAsync(deg, 0, NN * sizeof(float), stream);
    deg_kernel<<<(NE + 255) / 256, 256, 0, stream>>>(dstv, deg);
    invdeg_kernel<<<(NN + 255) / 256, 256, 0, stream>>>(deg);
    init_x_kernel<<<NN * DD / 1024, 256, 0, stream>>>(x);

    for (int l = 0; l < LL; ++l) {
        hipMemsetAsync(agg, 0, (size_t)RR * NN * DD * sizeof(float), stream);
        scatter_kernel<<<NE / 4, 256, 0, stream>>>(srcv, dstv, typev, ee,
            We + (size_t)l * EED * DD, x, agg);
        gemm_ln_kernel<<<NN / BM, 256, 0, stream>>>(agg,
            W + (size_t)l * RR * DD * DD, Wself + (size_t)l * DD * DD,
            deg, gamma + (size_t)l * DD, beta + (size_t)l * DD, x);
    }
    score_kernel<<<(BB * KK) / 4, 256, 0, stream>>>(batch, x, rel_emb, out);
}

// Round 2
// 4862.023 us; speedup vs baseline: 2.2584x; 2.2584x over previous
//
#include <hip/hip_runtime.h>
#include <hip/hip_bf16.h>

#define NN 20000
#define NE 320000
#define RR 8
#define DD 256
#define LL 6
#define EED 32
#define BB 64
#define KK 32
#define MM (NN * RR)        // 160000 segments, key = dst*8 + rel
#define NSB 79              // scan blocks: ceil(160000 / 2048)

// ---------------- CSR build (once per call) ----------------

__global__ __launch_bounds__(256) void hist_kernel(const int* __restrict__ dstv,
                                                   const int* __restrict__ typev,
                                                   int* __restrict__ hist) {
    int e = blockIdx.x * 256 + threadIdx.x;
    if (e < NE) atomicAdd(&hist[dstv[e] * 8 + typev[e]], 1);
}

// block scans 2048 elements (256 thr x 8), writes exclusive prefix + block sum
__global__ __launch_bounds__(256) void scan1_kernel(const int* __restrict__ hist,
                                                    int* __restrict__ excl,
                                                    int* __restrict__ bsums) {
    __shared__ int tmp[256];
    int tid = threadIdx.x;
    int base = blockIdx.x * 2048 + tid * 8;
    int v[8]; int s = 0;
#pragma unroll
    for (int i = 0; i < 8; ++i) {
        v[i] = (base + i < MM) ? hist[base + i] : 0;
        s += v[i];
    }
    tmp[tid] = s;
    __syncthreads();
    for (int off = 1; off < 256; off <<= 1) {
        int t = (tid >= off) ? tmp[tid - off] : 0;
        __syncthreads();
        tmp[tid] += t;
        __syncthreads();
    }
    int run = tmp[tid] - s;   // exclusive prefix of this thread's chunk
#pragma unroll
    for (int i = 0; i < 8; ++i) {
        if (base + i < MM) excl[base + i] = run;
        run += v[i];
    }
    if (tid == 255) bsums[blockIdx.x] = tmp[255];
}

__global__ __launch_bounds__(128) void scan2_kernel(int* __restrict__ bsums) {
    __shared__ int tmp[128];
    int tid = threadIdx.x;
    int orig = (tid < NSB) ? bsums[tid] : 0;
    tmp[tid] = orig;
    __syncthreads();
    for (int off = 1; off < 128; off <<= 1) {
        int t = (tid >= off) ? tmp[tid - off] : 0;
        __syncthreads();
        tmp[tid] += t;
        __syncthreads();
    }
    if (tid < NSB) bsums[tid] = tmp[tid] - orig;   // exclusive
}

__global__ __launch_bounds__(256) void add_off_kernel(const int* __restrict__ excl,
                                                      const int* __restrict__ bsums,
                                                      int* __restrict__ seg_start,
                                                      int* __restrict__ cursor) {
    int i = blockIdx.x * 256 + threadIdx.x;
    if (i < MM) {
        int v = excl[i] + bsums[i >> 11];
        seg_start[i] = v;
        cursor[i] = v;
    }
    if (i == 0) seg_start[MM] = NE;
}

__global__ __launch_bounds__(256) void sort_scatter_kernel(
    const int* __restrict__ srcv, const int* __restrict__ dstv,
    const int* __restrict__ typev, int* __restrict__ cursor,
    int* __restrict__ esrc, int* __restrict__ eid) {
    int e = blockIdx.x * 256 + threadIdx.x;
    if (e < NE) {
        int key = dstv[e] * 8 + typev[e];
        int pos = atomicAdd(&cursor[key], 1);
        esrc[pos] = srcv[e];
        eid[pos]  = e;
    }
}

__global__ __launch_bounds__(256) void invdeg_kernel(const int* __restrict__ seg_start,
                                                     float* __restrict__ invdeg) {
    int i = blockIdx.x * 256 + threadIdx.x;
    if (i < NN) {
        int d = seg_start[i * 8 + 8] - seg_start[i * 8];
        invdeg[i] = 1.0f / (float)max(d, 1);
    }
}

// ---------------- once-per-call precomputes ----------------

// eagg[n][r*32+j] = invdeg[n] * sum_{edges in seg (n,r)} ee[e][j]
__global__ __launch_bounds__(256) void eagg_kernel(
    const int* __restrict__ seg_start, const int* __restrict__ eid,
    const float* __restrict__ ee, const float* __restrict__ invdeg,
    float* __restrict__ eagg) {
    int tid = threadIdx.x;
    int s = blockIdx.x * 8 + (tid >> 5);     // 8 segments per block, 32 lanes each
    int j = tid & 31;
    int n = s >> 3, r = s & 7;
    int j0 = seg_start[s], j1 = seg_start[s + 1];
    float sum = 0.0f;
    for (int p = j0; p < j1; ++p)
        sum += ee[eid[p] * EED + j];
    eagg[n * DD + r * EED + j] = sum * invdeg[n];
}

// Whe[l][(r*32+j)][f] = sum_d We[l][j][d] * W[l][r][d][f]
__global__ __launch_bounds__(256) void whe_kernel(const float* __restrict__ We,
                                                  const float* __restrict__ W,
                                                  float* __restrict__ Whe) {
    __shared__ float WeS[EED * DD];
    int l = blockIdx.x >> 3, r = blockIdx.x & 7;
    int tid = threadIdx.x;
    const float4* We4 = (const float4*)(We + (size_t)l * EED * DD);
#pragma unroll
    for (int i = 0; i < 8; ++i) ((float4*)WeS)[tid + i * 256] = We4[tid + i * 256];
    __syncthreads();
    const float* Wr = W + ((size_t)l * 8 + r) * DD * DD;
    float acc[EED];
#pragma unroll
    for (int j = 0; j < EED; ++j) acc[j] = 0.0f;
    for (int d = 0; d < DD; ++d) {
        float w = Wr[d * DD + tid];
#pragma unroll
        for (int j = 0; j < EED; ++j) acc[j] += WeS[j * DD + d] * w;
    }
    float* outp = Whe + (size_t)l * DD * DD + r * EED * DD + tid;
#pragma unroll
    for (int j = 0; j < EED; ++j) outp[j * DD] = acc[j];
}

__global__ __launch_bounds__(256) void init_x_kernel(float* __restrict__ x) {
    int i = blockIdx.x * 256 + threadIdx.x;
    ((float4*)x)[i] = make_float4(1.f, 1.f, 1.f, 1.f);
}

// ---------------- fused per-layer kernel ----------------
// Block = 32 nodes. Phases: p=0 self (A=x, B=Wself), p=1..8 (A=xagg_r built
// from CSR in LDS, scaled by invdeg; B=W[l][r]), p=9 (A=eagg rows; B=Whe[l]).
// Unified K accumulate, then LN+ReLU+residual. x double-buffered.
__global__ __launch_bounds__(256, 2) void fused_layer_kernel(
    const int* __restrict__ seg_start, const int* __restrict__ esrc,
    const float* __restrict__ xin, const float* __restrict__ invdeg,
    const float* __restrict__ eagg, const float* __restrict__ Wl,
    const float* __restrict__ Wsl, const float* __restrict__ Whel,
    const float* __restrict__ gl, const float* __restrict__ bl,
    float* __restrict__ xout) {
    __shared__ float As[32 * DD];
    __shared__ float Bs[32 * DD];
    int tid = threadIdx.x;
    int row0 = blockIdx.x * 32;
    int tr = tid >> 5, tc = tid & 31;
    int wave = tid >> 6, lane = tid & 63;
    float acc[4][8] = {};

    for (int p = 0; p < 10; ++p) {
        const float* Bsrc;
        if (p == 0) {
            const float4* xr = (const float4*)xin + (size_t)row0 * 64;
#pragma unroll
            for (int i = 0; i < 8; ++i) ((float4*)As)[tid + i * 256] = xr[tid + i * 256];
            Bsrc = Wsl;
        } else if (p <= 8) {
            int r = p - 1;
            for (int nl = wave * 8; nl < wave * 8 + 8; ++nl) {
                int s = (row0 + nl) * 8 + r;
                int j0 = seg_start[s], j1 = seg_start[s + 1];
                float4 v = make_float4(0.f, 0.f, 0.f, 0.f);
                for (int j = j0; j < j1; ++j) {
                    int src = esrc[j];
                    float4 xv = *(const float4*)&xin[(size_t)src * DD + lane * 4];
                    v.x += xv.x; v.y += xv.y; v.z += xv.z; v.w += xv.w;
                }
                float idg = invdeg[row0 + nl];
                v.x *= idg; v.y *= idg; v.z *= idg; v.w *= idg;
                *(float4*)&As[nl * DD + lane * 4] = v;
            }
            Bsrc = Wl + (size_t)r * DD * DD;
        } else {
            const float4* er = (const float4*)eagg + (size_t)row0 * 64;
#pragma unroll
            for (int i = 0; i < 8; ++i) ((float4*)As)[tid + i * 256] = er[tid + i * 256];
            Bsrc = Whel;
        }
        __syncthreads();

        for (int kb = 0; kb < DD; kb += 32) {
            const float4* Bp = (const float4*)(Bsrc + (size_t)kb * DD);
#pragma unroll
            for (int i = 0; i < 8; ++i) ((float4*)Bs)[tid + i * 256] = Bp[tid + i * 256];
            __syncthreads();
#pragma unroll
            for (int k = 0; k < 32; ++k) {
                float4 b0 = *(float4*)&Bs[k * DD + tc * 4];
                float4 b1 = *(float4*)&Bs[k * DD + 128 + tc * 4];
#pragma unroll
                for (int i = 0; i < 4; ++i) {
                    float a = As[(tr * 4 + i) * DD + kb + k];
                    acc[i][0] += a * b0.x; acc[i][1] += a * b0.y;
                    acc[i][2] += a * b0.z; acc[i][3] += a * b0.w;
                    acc[i][4] += a * b1.x; acc[i][5] += a * b1.y;
                    acc[i][6] += a * b1.z; acc[i][7] += a * b1.w;
                }
            }
            __syncthreads();
        }
    }

    // epilogue: dump h into Bs, LN + relu + residual
#pragma unroll
    for (int i = 0; i < 4; ++i) {
        int row = tr * 4 + i;
        *(float4*)&Bs[row * DD + tc * 4]       = make_float4(acc[i][0], acc[i][1], acc[i][2], acc[i][3]);
        *(float4*)&Bs[row * DD + 128 + tc * 4] = make_float4(acc[i][4], acc[i][5], acc[i][6], acc[i][7]);
    }
    __syncthreads();
    float4 g  = *(const float4*)&gl[lane * 4];
    float4 bb = *(const float4*)&bl[lane * 4];
#pragma unroll
    for (int rr = 0; rr < 8; ++rr) {
        int row = wave * 8 + rr;
        float4 v = *(float4*)&Bs[row * DD + lane * 4];
        float s = v.x + v.y + v.z + v.w;
        float q = v.x * v.x + v.y * v.y + v.z * v.z + v.w * v.w;
#pragma unroll
        for (int off = 32; off; off >>= 1) {
            s += __shfl_xor(s, off);
            q += __shfl_xor(q, off);
        }
        float mu  = s * (1.0f / DD);
        float var = q * (1.0f / DD) - mu * mu;
        float rs  = rsqrtf(var + 1e-5f);
        size_t xi = (size_t)(row0 + row) * DD + lane * 4;
        float4 xv = *(const float4*)&xin[xi];
        float4 o;
        o.x = fmaxf((v.x - mu) * rs * g.x + bb.x, 0.0f) + xv.x;
        o.y = fmaxf((v.y - mu) * rs * g.y + bb.y, 0.0f) + xv.y;
        o.z = fmaxf((v.z - mu) * rs * g.z + bb.z, 0.0f) + xv.z;
        o.w = fmaxf((v.w - mu) * rs * g.w + bb.w, 0.0f) + xv.w;
        *(float4*)&xout[xi] = o;
    }
}

__global__ __launch_bounds__(256) void score_kernel(
    const int* __restrict__ batch, const float* __restrict__ x,
    const float* __restrict__ rel_emb, float* __restrict__ out) {
    int tid = threadIdx.x;
    int wave = tid >> 6, lane = tid & 63;
    int idx = blockIdx.x * 4 + wave;
    int s = batch[idx * 3 + 0], t = batch[idx * 3 + 1], r = batch[idx * 3 + 2];
    float4 sv = *(const float4*)&x[(size_t)s * DD + lane * 4];
    float4 tv = *(const float4*)&x[(size_t)t * DD + lane * 4];
    float4 rv = *(const float4*)&rel_emb[(size_t)r * DD + lane * 4];
    float sum = sv.x * rv.x * tv.x + sv.y * rv.y * tv.y +
                sv.z * rv.z * tv.z + sv.w * rv.w * tv.w;
#pragma unroll
    for (int off = 32; off; off >>= 1) sum += __shfl_xor(sum, off);
    if (lane == 0) out[idx] = sum;
}

extern "C" void kernel_launch(void* const* d_in, const int* in_sizes, int n_in,
                              void* d_out, int out_size, void* d_ws, size_t ws_size,
                              hipStream_t stream) {
    const int*   edge_index = (const int*)d_in[0];
    const int*   srcv   = edge_index;
    const int*   dstv   = edge_index + NE;
    const int*   typev  = (const int*)d_in[1];
    const float* ee     = (const float*)d_in[2];
    const int*   batch  = (const int*)d_in[3];
    const float* W      = (const float*)d_in[4];
    const float* Wself  = (const float*)d_in[5];
    const float* We     = (const float*)d_in[6];
    const float* gamma  = (const float*)d_in[7];
    const float* beta   = (const float*)d_in[8];
    const float* rel_emb= (const float*)d_in[9];
    float* out = (float*)d_out;

    // workspace layout (floats / ints)
    float* xA     = (float*)d_ws;                         // N*D
    float* xB     = xA + (size_t)NN * DD;                 // N*D
    float* eagg   = xB + (size_t)NN * DD;                 // N*256
    float* Whe    = eagg + (size_t)NN * DD;               // L*256*256
    float* invdeg = Whe + (size_t)LL * DD * DD;           // N
    int* hist      = (int*)(invdeg + NN);                 // M
    int* excl      = hist + MM;                           // M
    int* seg_start = excl + MM;                           // M+1
    int* cursor    = seg_start + MM + 1;                  // M
    int* bsums     = cursor + MM;                         // 256
    int* esrc      = bsums + 256;                         // E
    int* eid       = esrc + NE;                           // E

    // ---- CSR build ----
    hipMemsetAsync(hist, 0, MM * sizeof(int), stream);
    hist_kernel<<<(NE + 255) / 256, 256, 0, stream>>>(dstv, typev, hist);
    scan1_kernel<<<NSB, 256, 0, stream>>>(hist, excl, bsums);
    scan2_kernel<<<1, 128, 0, stream>>>(bsums);
    add_off_kernel<<<(MM + 255) / 256, 256, 0, stream>>>(excl, bsums, seg_start, cursor);
    invdeg_kernel<<<(NN + 255) / 256, 256, 0, stream>>>(seg_start, invdeg);
    sort_scatter_kernel<<<(NE + 255) / 256, 256, 0, stream>>>(srcv, dstv, typev, cursor, esrc, eid);

    // ---- precomputes ----
    eagg_kernel<<<MM / 8, 256, 0, stream>>>(seg_start, eid, ee, invdeg, eagg);
    whe_kernel<<<LL * RR, 256, 0, stream>>>(We, W, Whe);
    init_x_kernel<<<NN * DD / 1024, 256, 0, stream>>>(xA);

    // ---- layers (x double-buffered) ----
    float* xin = xA;
    float* xout = xB;
    for (int l = 0; l < LL; ++l) {
        fused_layer_kernel<<<NN / 32, 256, 0, stream>>>(
            seg_start, esrc, xin, invdeg, eagg,
            W + (size_t)l * RR * DD * DD, Wself + (size_t)l * DD * DD,
            Whe + (size_t)l * DD * DD,
            gamma + (size_t)l * DD, beta + (size_t)l * DD, xout);
        float* t = xin; xin = xout; xout = t;
    }
    // after even number of layers, final x is back in xA (== xin)
    score_kernel<<<(BB * KK) / 4, 256, 0, stream>>>(batch, xin, rel_emb, out);
}

// Round 3
// 1012.134 us; speedup vs baseline: 10.8489x; 4.8037x over previous
//
#include <hip/hip_runtime.h>
#include <hip/hip_bf16.h>

#define NN 20000
#define NP 20032            // padded to 64*313
#define NE 320000
#define RR 8
#define DD 256
#define LL 6
#define EED 32
#define BB 64
#define KK 32
#define MM (NN * RR)        // 160000 segments, key = dst*8 + rel
#define NSB 79              // scan blocks: ceil(160000 / 2048)
#define NB 313              // row blocks of 64

typedef __bf16 bf8 __attribute__((ext_vector_type(8)));
typedef float f4 __attribute__((ext_vector_type(4)));

__device__ inline float lo2f(unsigned v) { return __uint_as_float(v << 16); }
__device__ inline float hi2f(unsigned v) { return __uint_as_float(v & 0xffff0000u); }
__device__ inline unsigned short f2bf(float f) {
    unsigned u = __float_as_uint(f);
    return (unsigned short)((u + 0x7fff + ((u >> 16) & 1)) >> 16);
}
__device__ inline unsigned pack2(float lo, float hi) {
    return (unsigned)f2bf(lo) | ((unsigned)f2bf(hi) << 16);
}

// ---------------- CSR build (once per call) ----------------

__global__ __launch_bounds__(256) void hist_kernel(const int* __restrict__ dstv,
                                                   const int* __restrict__ typev,
                                                   int* __restrict__ hist) {
    int e = blockIdx.x * 256 + threadIdx.x;
    if (e < NE) atomicAdd(&hist[dstv[e] * 8 + typev[e]], 1);
}

__global__ __launch_bounds__(256) void scan1_kernel(const int* __restrict__ hist,
                                                    int* __restrict__ excl,
                                                    int* __restrict__ bsums) {
    __shared__ int tmp[256];
    int tid = threadIdx.x;
    int base = blockIdx.x * 2048 + tid * 8;
    int v[8]; int s = 0;
#pragma unroll
    for (int i = 0; i < 8; ++i) {
        v[i] = (base + i < MM) ? hist[base + i] : 0;
        s += v[i];
    }
    tmp[tid] = s;
    __syncthreads();
    for (int off = 1; off < 256; off <<= 1) {
        int t = (tid >= off) ? tmp[tid - off] : 0;
        __syncthreads();
        tmp[tid] += t;
        __syncthreads();
    }
    int run = tmp[tid] - s;
#pragma unroll
    for (int i = 0; i < 8; ++i) {
        if (base + i < MM) excl[base + i] = run;
        run += v[i];
    }
    if (tid == 255) bsums[blockIdx.x] = tmp[255];
}

__global__ __launch_bounds__(128) void scan2_kernel(int* __restrict__ bsums) {
    __shared__ int tmp[128];
    int tid = threadIdx.x;
    int orig = (tid < NSB) ? bsums[tid] : 0;
    tmp[tid] = orig;
    __syncthreads();
    for (int off = 1; off < 128; off <<= 1) {
        int t = (tid >= off) ? tmp[tid - off] : 0;
        __syncthreads();
        tmp[tid] += t;
        __syncthreads();
    }
    if (tid < NSB) bsums[tid] = tmp[tid] - orig;
}

__global__ __launch_bounds__(256) void add_off_kernel(const int* __restrict__ excl,
                                                      const int* __restrict__ bsums,
                                                      int* __restrict__ seg_start,
                                                      int* __restrict__ cursor) {
    int i = blockIdx.x * 256 + threadIdx.x;
    if (i < MM) {
        int v = excl[i] + bsums[i >> 11];
        seg_start[i] = v;
        cursor[i] = v;
    }
    if (i == 0) seg_start[MM] = NE;
}

__global__ __launch_bounds__(256) void sort_scatter_kernel(
    const int* __restrict__ srcv, const int* __restrict__ dstv,
    const int* __restrict__ typev, int* __restrict__ cursor,
    int* __restrict__ esrc, int* __restrict__ eid) {
    int e = blockIdx.x * 256 + threadIdx.x;
    if (e < NE) {
        int key = dstv[e] * 8 + typev[e];
        int pos = atomicAdd(&cursor[key], 1);
        esrc[pos] = srcv[e];
        eid[pos]  = e;
    }
}

__global__ __launch_bounds__(256) void invdeg_kernel(const int* __restrict__ seg_start,
                                                     float* __restrict__ invdeg) {
    int i = blockIdx.x * 256 + threadIdx.x;
    if (i < NN) {
        int d = seg_start[i * 8 + 8] - seg_start[i * 8];
        invdeg[i] = 1.0f / (float)max(d, 1);
    }
}

// ---------------- once-per-call precomputes ----------------

// eaggbf[n][r*32+j] = bf16( invdeg[n] * sum_{edges in seg (n,r)} ee[e][j] )
__global__ __launch_bounds__(256) void eagg_kernel(
    const int* __restrict__ seg_start, const int* __restrict__ eid,
    const float* __restrict__ ee, const float* __restrict__ invdeg,
    unsigned short* __restrict__ eaggbf) {
    int tid = threadIdx.x;
    int s = blockIdx.x * 8 + (tid >> 5);
    int j = tid & 31;
    int n = s >> 3, r = s & 7;
    int j0 = seg_start[s], j1 = seg_start[s + 1];
    float sum = 0.0f;
    for (int p = j0; p < j1; ++p)
        sum += ee[eid[p] * EED + j];
    eaggbf[(size_t)n * DD + r * EED + j] = f2bf(sum * invdeg[n]);
}

// Whe[l][(r*32+j)][f] = sum_d We[l][j][d] * W[l][r][d][f]
__global__ __launch_bounds__(256) void whe_kernel(const float* __restrict__ We,
                                                  const float* __restrict__ W,
                                                  float* __restrict__ Whe) {
    __shared__ float WeS[EED * DD];
    int l = blockIdx.x >> 3, r = blockIdx.x & 7;
    int tid = threadIdx.x;
    const float4* We4 = (const float4*)(We + (size_t)l * EED * DD);
#pragma unroll
    for (int i = 0; i < 8; ++i) ((float4*)WeS)[tid + i * 256] = We4[tid + i * 256];
    __syncthreads();
    const float* Wr = W + ((size_t)l * 8 + r) * DD * DD;
    float acc[EED];
#pragma unroll
    for (int j = 0; j < EED; ++j) acc[j] = 0.0f;
    for (int d = 0; d < DD; ++d) {
        float w = Wr[d * DD + tid];
#pragma unroll
        for (int j = 0; j < EED; ++j) acc[j] += WeS[j * DD + d] * w;
    }
    float* outp = Whe + (size_t)l * DD * DD + r * EED * DD + tid;
#pragma unroll
    for (int j = 0; j < EED; ++j) outp[j * DD] = acc[j];
}

// B pre-swizzle into MFMA fragment order (bf16):
// Bsw[l][(((p*8+kb)*4+quad)*256+f)*8+j] = B_l[p*256+kb*32+quad*8+j][f]
__global__ __launch_bounds__(256) void bswz_kernel(const float* __restrict__ W,
                                                   const float* __restrict__ Wself,
                                                   const float* __restrict__ Whe,
                                                   unsigned short* __restrict__ Bsw) {
    int gid = blockIdx.x * 256 + threadIdx.x;
    int f = gid & 255;
    int t = gid >> 8;
    int quad = t & 3; t >>= 2;
    int kb = t & 7; t >>= 3;
    int p = t % 10, l = t / 10;
    const float* base = (p < 8) ? W + (size_t)(l * 8 + p) * DD * DD
                      : (p == 8) ? Wself + (size_t)l * DD * DD
                                 : Whe + (size_t)l * DD * DD;
    int k0 = kb * 32 + quad * 8;
    unsigned pk[4];
#pragma unroll
    for (int jj = 0; jj < 4; ++jj)
        pk[jj] = pack2(base[(size_t)(k0 + 2 * jj) * DD + f],
                       base[(size_t)(k0 + 2 * jj + 1) * DD + f]);
    uint4 v = make_uint4(pk[0], pk[1], pk[2], pk[3]);
    *(uint4*)&Bsw[(size_t)gid * 8] = v;
}

__global__ __launch_bounds__(256) void init_x_kernel(float* __restrict__ x,
                                                     unsigned short* __restrict__ xbf) {
    int i = blockIdx.x * 256 + threadIdx.x;   // one float4 / 4 bf16 per thread
    ((float4*)x)[i] = make_float4(1.f, 1.f, 1.f, 1.f);
    ((uint2*)xbf)[i] = make_uint2(0x3f803f80u, 0x3f803f80u);
}

// ---------------- per-layer pass 1: CSR segment-sum into bf16 agg ----------------
// one wave per segment (n,r); lane covers 4 features (8B)
__global__ __launch_bounds__(256) void agg_build_kernel(
    const int* __restrict__ seg_start, const int* __restrict__ esrc,
    const unsigned short* __restrict__ xbf, const float* __restrict__ invdeg,
    unsigned short* __restrict__ aggbf) {
    int tid = threadIdx.x;
    int wave = tid >> 6, lane = tid & 63;
    int s = blockIdx.x * 4 + wave;
    int n = s >> 3, r = s & 7;
    int j0 = seg_start[s], j1 = seg_start[s + 1];
    float a0 = 0.f, a1 = 0.f, a2 = 0.f, a3 = 0.f;
    for (int j = j0; j < j1; ++j) {
        int src = esrc[j];
        uint2 v = *(const uint2*)&xbf[(size_t)src * DD + lane * 4];
        a0 += lo2f(v.x); a1 += hi2f(v.x);
        a2 += lo2f(v.y); a3 += hi2f(v.y);
    }
    float idg = invdeg[n];
    uint2 o = make_uint2(pack2(a0 * idg, a1 * idg), pack2(a2 * idg, a3 * idg));
    *(uint2*)&aggbf[((size_t)r * NP + n) * DD + lane * 4] = o;
}

// ---------------- per-layer pass 2: MFMA GEMM + LN + ReLU + residual ----------------
// block = 64 rows x 256 cols, 4 waves (wave w -> cols w*64..w*64+63, 4x4 16x16 tiles)
// K = 2560 in 10 phases of 256 (8 relations, self, folded edge-term)
__global__ __launch_bounds__(256) void layer_mfma_kernel(
    const unsigned short* __restrict__ aggbf, const unsigned short* __restrict__ xbf,
    const unsigned short* __restrict__ eaggbf, const unsigned short* __restrict__ Bswl,
    const float* __restrict__ xin, const float* __restrict__ gl,
    const float* __restrict__ bl, float* __restrict__ xout,
    unsigned short* __restrict__ xbfout) {
    __shared__ __align__(16) unsigned char smem[32768];  // A stage (64x512B) / h stage (32x256 f32)
    unsigned short* As = (unsigned short*)smem;
    float* Hs = (float*)smem;
    int tid = threadIdx.x;
    int wave = tid >> 6, lane = tid & 63;
    int row0 = blockIdx.x * 64;
    int m = lane & 15, quad = lane >> 4;
    int sr = tid >> 5, sc = tid & 31;       // staging coords: 8 rows x 32 granules
    f4 acc[4][4] = {};

    for (int p = 0; p < 10; ++p) {
        const unsigned short* srcA =
            (p < 8)  ? aggbf + ((size_t)p * NP + row0) * DD
          : (p == 8) ? xbf + (size_t)row0 * DD
                     : eaggbf + (size_t)row0 * DD;
        __syncthreads();
        // stage A phase tile 64x256 bf16, xor-swizzled 16B granules
#pragma unroll
        for (int i = 0; i < 8; ++i) {
            int row = i * 8 + sr;
            uint4 v = *(const uint4*)&srcA[(size_t)row * DD + sc * 8];
            *(uint4*)&smem[row * 512 + ((sc ^ (row & 31)) * 16)] = v;
        }
        __syncthreads();
        const unsigned short* Bp = Bswl + (size_t)p * 65536;
        bf8 bnext[4];
#pragma unroll
        for (int nt = 0; nt < 4; ++nt)
            bnext[nt] = *(const bf8*)&Bp[((size_t)quad * 256 + wave * 64 + nt * 16 + m) * 8];
        for (int kb = 0; kb < 8; ++kb) {
            bf8 bcur[4];
#pragma unroll
            for (int nt = 0; nt < 4; ++nt) bcur[nt] = bnext[nt];
            if (kb < 7) {
#pragma unroll
                for (int nt = 0; nt < 4; ++nt)
                    bnext[nt] = *(const bf8*)&Bp[(((size_t)(kb + 1) * 4 + quad) * 256 + wave * 64 + nt * 16 + m) * 8];
            }
            bf8 afr[4];
#pragma unroll
            for (int mt = 0; mt < 4; ++mt) {
                int rowl = mt * 16 + m;
                afr[mt] = *(bf8*)&smem[rowl * 512 + (((kb * 4 + quad) ^ (rowl & 31)) * 16)];
            }
#pragma unroll
            for (int mt = 0; mt < 4; ++mt)
#pragma unroll
                for (int nt = 0; nt < 4; ++nt)
                    acc[mt][nt] = __builtin_amdgcn_mfma_f32_16x16x32_bf16(afr[mt], bcur[nt], acc[mt][nt], 0, 0, 0);
        }
    }

    // epilogue: two halves of 32 rows through LDS; LN + ReLU + residual
    float4 g  = *(const float4*)&gl[lane * 4];
    float4 bb = *(const float4*)&bl[lane * 4];
#pragma unroll
    for (int h = 0; h < 2; ++h) {
        __syncthreads();
#pragma unroll
        for (int mt = 2 * h; mt < 2 * h + 2; ++mt)
#pragma unroll
            for (int nt = 0; nt < 4; ++nt)
#pragma unroll
                for (int rg = 0; rg < 4; ++rg)
                    Hs[(mt * 16 + quad * 4 + rg - 32 * h) * DD + wave * 64 + nt * 16 + m] = acc[mt][nt][rg];
        __syncthreads();
#pragma unroll
        for (int rr = 0; rr < 8; ++rr) {
            int row = wave * 8 + rr;
            float4 v = *(float4*)&Hs[row * DD + lane * 4];
            float s = v.x + v.y + v.z + v.w;
            float q = v.x * v.x + v.y * v.y + v.z * v.z + v.w * v.w;
#pragma unroll
            for (int off = 32; off; off >>= 1) {
                s += __shfl_xor(s, off);
                q += __shfl_xor(q, off);
            }
            float mu  = s * (1.0f / DD);
            float var = q * (1.0f / DD) - mu * mu;
            float rs  = rsqrtf(var + 1e-5f);
            int grow = row0 + 32 * h + row;
            size_t xi = (size_t)grow * DD + lane * 4;
            float4 xv = *(const float4*)&xin[xi];
            float4 o;
            o.x = fmaxf((v.x - mu) * rs * g.x + bb.x, 0.0f) + xv.x;
            o.y = fmaxf((v.y - mu) * rs * g.y + bb.y, 0.0f) + xv.y;
            o.z = fmaxf((v.z - mu) * rs * g.z + bb.z, 0.0f) + xv.z;
            o.w = fmaxf((v.w - mu) * rs * g.w + bb.w, 0.0f) + xv.w;
            *(float4*)&xout[xi] = o;
            *(uint2*)&xbfout[xi] = make_uint2(pack2(o.x, o.y), pack2(o.z, o.w));
        }
    }
}

__global__ __launch_bounds__(256) void score_kernel(
    const int* __restrict__ batch, const float* __restrict__ x,
    const float* __restrict__ rel_emb, float* __restrict__ out) {
    int tid = threadIdx.x;
    int wave = tid >> 6, lane = tid & 63;
    int idx = blockIdx.x * 4 + wave;
    int s = batch[idx * 3 + 0], t = batch[idx * 3 + 1], r = batch[idx * 3 + 2];
    float4 sv = *(const float4*)&x[(size_t)s * DD + lane * 4];
    float4 tv = *(const float4*)&x[(size_t)t * DD + lane * 4];
    float4 rv = *(const float4*)&rel_emb[(size_t)r * DD + lane * 4];
    float sum = sv.x * rv.x * tv.x + sv.y * rv.y * tv.y +
                sv.z * rv.z * tv.z + sv.w * rv.w * tv.w;
#pragma unroll
    for (int off = 32; off; off >>= 1) sum += __shfl_xor(sum, off);
    if (lane == 0) out[idx] = sum;
}

extern "C" void kernel_launch(void* const* d_in, const int* in_sizes, int n_in,
                              void* d_out, int out_size, void* d_ws, size_t ws_size,
                              hipStream_t stream) {
    const int*   edge_index = (const int*)d_in[0];
    const int*   srcv   = edge_index;
    const int*   dstv   = edge_index + NE;
    const int*   typev  = (const int*)d_in[1];
    const float* ee     = (const float*)d_in[2];
    const int*   batch  = (const int*)d_in[3];
    const float* W      = (const float*)d_in[4];
    const float* Wself  = (const float*)d_in[5];
    const float* We     = (const float*)d_in[6];
    const float* gamma  = (const float*)d_in[7];
    const float* beta   = (const float*)d_in[8];
    const float* rel_emb= (const float*)d_in[9];
    float* out = (float*)d_out;

    // workspace layout
    float* xA     = (float*)d_ws;                          // NP*256 f32
    float* xB     = xA + (size_t)NP * DD;                  // NP*256 f32
    float* Whe    = xB + (size_t)NP * DD;                  // L*256*256 f32
    float* invdeg = Whe + (size_t)LL * DD * DD;            // NN f32
    unsigned short* aggbf  = (unsigned short*)(invdeg + NN);          // 8*NP*256
    unsigned short* xbfA   = aggbf + (size_t)RR * NP * DD;            // NP*256
    unsigned short* xbfB   = xbfA + (size_t)NP * DD;                  // NP*256
    unsigned short* eaggbf = xbfB + (size_t)NP * DD;                  // NP*256
    unsigned short* Bsw    = eaggbf + (size_t)NP * DD;                // L*2560*256
    int* hist      = (int*)(Bsw + (size_t)LL * 2560 * DD);            // M
    int* excl      = hist + MM;
    int* seg_start = excl + MM;                                       // M+1
    int* cursor    = seg_start + MM + 1;
    int* bsums     = cursor + MM;                                     // 256
    int* esrc      = bsums + 256;                                     // E
    int* eid       = esrc + NE;                                       // E

    // ---- CSR build ----
    hipMemsetAsync(hist, 0, MM * sizeof(int), stream);
    hist_kernel<<<(NE + 255) / 256, 256, 0, stream>>>(dstv, typev, hist);
    scan1_kernel<<<NSB, 256, 0, stream>>>(hist, excl, bsums);
    scan2_kernel<<<1, 128, 0, stream>>>(bsums);
    add_off_kernel<<<(MM + 255) / 256, 256, 0, stream>>>(excl, bsums, seg_start, cursor);
    invdeg_kernel<<<(NN + 255) / 256, 256, 0, stream>>>(seg_start, invdeg);
    sort_scatter_kernel<<<(NE + 255) / 256, 256, 0, stream>>>(srcv, dstv, typev, cursor, esrc, eid);

    // ---- precomputes ----
    eagg_kernel<<<MM / 8, 256, 0, stream>>>(seg_start, eid, ee, invdeg, eaggbf);
    whe_kernel<<<LL * RR, 256, 0, stream>>>(We, W, Whe);
    bswz_kernel<<<LL * 10 * 8 * 4, 256, 0, stream>>>(W, Wself, Whe, Bsw);
    init_x_kernel<<<(NP * DD / 4) / 256, 256, 0, stream>>>(xA, xbfA);

    // ---- layers (x double-buffered) ----
    float* xin = xA;  float* xout = xB;
    unsigned short* xbin = xbfA;  unsigned short* xbout = xbfB;
    for (int l = 0; l < LL; ++l) {
        agg_build_kernel<<<MM / 4, 256, 0, stream>>>(seg_start, esrc, xbin, invdeg, aggbf);
        layer_mfma_kernel<<<NB, 256, 0, stream>>>(aggbf, xbin, eaggbf,
            Bsw + (size_t)l * 2560 * DD, xin,
            gamma + (size_t)l * DD, beta + (size_t)l * DD, xout, xbout);
        float* t = xin; xin = xout; xout = t;
        unsigned short* tb = xbin; xbin = xbout; xbout = tb;
    }
    score_kernel<<<(BB * KK) / 4, 256, 0, stream>>>(batch, xin, rel_emb, out);
}